// Round 3
// baseline (478.443 us; speedup 1.0000x reference)
//
#include <hip/hip_runtime.h>
#include <hip/hip_bf16.h>

typedef float f32x4 __attribute__((ext_vector_type(4)));
typedef short bf16x8 __attribute__((ext_vector_type(8)));
typedef unsigned short ushort_t;

// ---------- bf16 helpers (RNE) ----------
__device__ __forceinline__ ushort_t f2bf(float f) {
    union { float f; unsigned u; } v; v.f = f;
    unsigned r = v.u + 0x7fffu + ((v.u >> 16) & 1u);
    return (ushort_t)(r >> 16);
}
__device__ __forceinline__ float bf2f(ushort_t h) {
    union { unsigned u; float f; } v; v.u = ((unsigned)h) << 16;
    return v.f;
}

// ---------- async global->LDS 16B/lane (wave-uniform LDS base + lane*16) ----------
__device__ __forceinline__ void async16(ushort_t* lds, const ushort_t* g) {
    __builtin_amdgcn_global_load_lds(
        (const __attribute__((address_space(1))) unsigned int*)g,
        (__attribute__((address_space(3))) unsigned int*)lds, 16, 0, 0);
}

// ---------- cast fp32 -> bf16, 8 elems/thread ----------
__global__ __launch_bounds__(256) void cast_bf16_kernel(const float* __restrict__ src,
                                                        ushort_t* __restrict__ dst, long n) {
    long i = ((long)blockIdx.x * 256 + threadIdx.x) * 8;
    if (i >= n) return;
    float4 a = *(const float4*)(src + i);
    float4 b = *(const float4*)(src + i + 4);
    ushort_t o[8];
    o[0]=f2bf(a.x); o[1]=f2bf(a.y); o[2]=f2bf(a.z); o[3]=f2bf(a.w);
    o[4]=f2bf(b.x); o[5]=f2bf(b.y); o[6]=f2bf(b.z); o[7]=f2bf(b.w);
    *(bf16x8*)(dst + i) = *(bf16x8*)o;
}

// ---------- cast 4 weight matrices (each 512x512) in one dispatch ----------
__global__ __launch_bounds__(256) void cast_w4_kernel(const float* __restrict__ s0,
                                                      const float* __restrict__ s1,
                                                      const float* __restrict__ s2,
                                                      const float* __restrict__ s3,
                                                      ushort_t* __restrict__ dst) {
    long idx = (long)blockIdx.x * 256 + threadIdx.x;          // 131072 threads
    int sel = (int)(idx >> 15);
    const float* s = sel == 0 ? s0 : sel == 1 ? s1 : sel == 2 ? s2 : s3;
    long off = (idx & 32767) * 8;
    float4 a = *(const float4*)(s + off);
    float4 b = *(const float4*)(s + off + 4);
    ushort_t o[8];
    o[0]=f2bf(a.x); o[1]=f2bf(a.y); o[2]=f2bf(a.z); o[3]=f2bf(a.w);
    o[4]=f2bf(b.x); o[5]=f2bf(b.y); o[6]=f2bf(b.z); o[7]=f2bf(b.w);
    *(bf16x8*)(dst + (long)sel * 262144 + off) = *(bf16x8*)o;
}

// ---------- pack both Wsr [C,C,2,2] -> bf16 B^T layout [c][tap*512+ci] ----------
__global__ __launch_bounds__(256) void pack_wsr2_kernel(const float* __restrict__ w0,
                                                        const float* __restrict__ w1,
                                                        ushort_t* __restrict__ out) {
    int idx = blockIdx.x * 256 + threadIdx.x;   // 2097152 total
    int sel = idx >> 20;
    const float* w = sel ? w1 : w0;
    int li = idx & 1048575;
    int c = li >> 11, k = li & 2047;
    int tap = k >> 9, ci = k & 511;
    out[idx] = f2bf(w[c * 2048 + ci * 4 + tap]);
}

// ---------- generic 128x128 bf16 MFMA GEMM: C = A[M,K] * B[N,K]^T + bias ----------
// Staging via global_load_lds width=16 (m97/m151 pattern). LDS is LINEAR
// [128][64] (gload_lds needs contiguous lane-order dest; padding forbidden).
// Fragment-read bank conflicts accepted: T2 swizzle is NULL at 2-phase (regime gate).
struct GemmJob {
    const ushort_t* A;
    const ushort_t* Bw;
    const float* bias;
    void* C;
    int omode;
};

template<bool GATHER>
__global__ __launch_bounds__(256) void gemm_bt(GemmJob j0, GemmJob j1,
                                               int M, int N, int K) {
    __shared__ __align__(16) ushort_t As[128][64];
    __shared__ __align__(16) ushort_t Bs[128][64];
    const GemmJob j = blockIdx.z == 0 ? j0 : j1;
    const int tid  = threadIdx.x;
    const int row0 = blockIdx.y * 128, col0 = blockIdx.x * 128;
    const int wave = tid >> 6, lane = tid & 63;
    const int rw = wave >> 1, cw = wave & 1;
    const int l15 = lane & 15, l4 = lane >> 4;
    const int srow = wave * 8 + (lane >> 3);     // staging row within 32-row group
    const int sc8  = (lane & 7) * 8;             // staging col (elems)

    f32x4 acc[4][4] = {};

    for (int k0 = 0; k0 < K; k0 += 64) {
        __syncthreads();                         // prev tile's reads done
#pragma unroll
        for (int p = 0; p < 4; ++p) {
            int r = p * 32 + srow;
            const ushort_t* ga;
            if (GATHER) {
                int gr = row0 + r;
                int b = gr >> 10, m = gr & 1023;
                int mh = m >> 5, mw = m & 31;
                int tap = k0 >> 9;
                int kh = tap >> 1, kw = tap & 1;
                ga = j.A + ((long)(b * 4096 + (2 * mh + kh) * 64 + (2 * mw + kw))) * 512
                         + (k0 & 511) + sc8;
            } else {
                ga = j.A + (long)(row0 + r) * K + k0 + sc8;
            }
            async16(&As[p * 32 + wave * 8][0], ga);
            async16(&Bs[p * 32 + wave * 8][0],
                    j.Bw + (long)(col0 + r) * K + k0 + sc8);
        }
        __syncthreads();                         // vmcnt(0) drained by compiler
#pragma unroll
        for (int ks = 0; ks < 2; ++ks) {
            bf16x8 af[4], bfr[4];
#pragma unroll
            for (int i = 0; i < 4; ++i)
                af[i] = *(const bf16x8*)&As[rw * 64 + i * 16 + l15][ks * 32 + l4 * 8];
#pragma unroll
            for (int jj = 0; jj < 4; ++jj)
                bfr[jj] = *(const bf16x8*)&Bs[cw * 64 + jj * 16 + l15][ks * 32 + l4 * 8];
#pragma unroll
            for (int i = 0; i < 4; ++i)
#pragma unroll
                for (int jj = 0; jj < 4; ++jj)
                    acc[i][jj] = __builtin_amdgcn_mfma_f32_16x16x32_bf16(af[i], bfr[jj],
                                                                         acc[i][jj], 0, 0, 0);
        }
    }
    // epilogue: C/D layout col=lane&15, row=(lane>>4)*4+reg  [m89-verified]
#pragma unroll
    for (int i = 0; i < 4; ++i) {
#pragma unroll
        for (int jj = 0; jj < 4; ++jj) {
            int col = col0 + cw * 64 + jj * 16 + l15;
            float bv = j.bias[col];
#pragma unroll
            for (int r = 0; r < 4; ++r) {
                int row = row0 + rw * 64 + i * 16 + l4 * 4 + r;
                float v = acc[i][jj][r] + bv;
                if (j.omode == 0) {
                    ((ushort_t*)j.C)[(long)row * N + col] = f2bf(v);
                } else if (j.omode == 1) {
                    ((float*)j.C)[(long)row * N + col] = v;
                } else {
                    int b = row >> 10, m = row & 1023;
                    int hh = col >> 6, dd = col & 63;
                    ((ushort_t*)j.C)[(((long)(b * 8 + hh) * 64 + dd) << 10) + m] = f2bf(v);
                }
            }
        }
    }
}

// ---------- in-place LayerNorm over rows of 512 (bf16), wave per row ----------
// rows 0..8191 use (g0,be0); rows 8192..16383 use (g1,be1)  (convk||convv contiguous)
__global__ __launch_bounds__(256) void ln_kernel(ushort_t* __restrict__ data,
                                                 const float* __restrict__ g0,
                                                 const float* __restrict__ be0,
                                                 const float* __restrict__ g1,
                                                 const float* __restrict__ be1) {
    int wave = threadIdx.x >> 6, lane = threadIdx.x & 63;
    long row = (long)blockIdx.x * 4 + wave;
    const float* g  = row < 8192 ? g0 : g1;
    const float* be = row < 8192 ? be0 : be1;
    ushort_t* p = data + row * 512 + lane * 8;
    bf16x8 raw = *(bf16x8*)p;
    ushort_t* rp = (ushort_t*)&raw;
    float v[8], s = 0.f, s2 = 0.f;
#pragma unroll
    for (int j = 0; j < 8; ++j) { v[j] = bf2f(rp[j]); s += v[j]; s2 += v[j] * v[j]; }
#pragma unroll
    for (int d = 1; d < 64; d <<= 1) { s += __shfl_xor(s, d); s2 += __shfl_xor(s2, d); }
    float mu  = s * (1.f / 512.f);
    float var = s2 * (1.f / 512.f) - mu * mu;
    float rs  = rsqrtf(var + 1e-5f);
    ushort_t o[8];
#pragma unroll
    for (int j = 0; j < 8; ++j) {
        int c = lane * 8 + j;
        o[j] = f2bf((v[j] - mu) * rs * g[c] + be[c]);
    }
    *(bf16x8*)p = *(bf16x8*)o;
}

// ---------- flash attention v5 (R1-exact, synchronous staging — PASSED) ----------
// Block = (b, head, 128 q-rows); wave owns 32 q-rows (2 n-blocks), sharing each
// K-fragment and V-fragment across both. Q fragments in registers.
// P = exp2(S * 0.125*log2e), packed by HW v_cvt_pk_bf16_f32.
// l = sum_m P via extra MFMA with ones-B.
__global__ __launch_bounds__(256, 3) void attn_kernel(const ushort_t* __restrict__ q,
                                                      const ushort_t* __restrict__ k,
                                                      const ushort_t* __restrict__ vt,
                                                      ushort_t* __restrict__ o) {
    __shared__ __align__(16) ushort_t Ks[128][72];
    __shared__ __align__(16) ushort_t Vs[64][136];   // V^T: [d][m]

    const int tid = threadIdx.x;
    const int wave = tid >> 6, lane = tid & 63;
    const int l15 = lane & 15, l4 = lane >> 4;
    const int n0 = blockIdx.x * 128;
    const int hh = blockIdx.y;
    const int b  = blockIdx.z;

    // Q fragments: wave's q-rows are n0 + wave*32 + nb*16 + l15 (unscaled bf16)
    bf16x8 bq[2][2];
#pragma unroll
    for (int nb = 0; nb < 2; ++nb)
#pragma unroll
        for (int ks = 0; ks < 2; ++ks)
            bq[nb][ks] = *(const bf16x8*)(
                q + (long)(b * 4096 + n0 + wave * 32 + nb * 16 + l15) * 512
                  + hh * 64 + ks * 32 + l4 * 8);

    f32x4 oacc[2][4] = {};
    f32x4 lacc[2] = {};
    union { bf16x8 v8; unsigned u[4]; } ones;
    ones.u[0] = ones.u[1] = ones.u[2] = ones.u[3] = 0x3F803F80u;
    const float EC = 0.18033688011112042f;   // 0.125 * log2(e)

    for (int c = 0; c < 8; ++c) {
        const int m0 = c * 128;
        __syncthreads();                    // previous chunk's LDS reads done
#pragma unroll
        for (int p = 0; p < 4; ++p) {       // K chunk [128 m][64 d]
            int qi = p * 256 + tid;
            int r = qi >> 3, c8 = (qi & 7) * 8;
            bf16x8 v = *(const bf16x8*)(k + (((long)(b * 1024 + m0 + r) * 8 + hh) << 6) + c8);
            *(bf16x8*)&Ks[r][c8] = v;
        }
#pragma unroll
        for (int p = 0; p < 4; ++p) {       // V^T chunk [64 d][128 m]
            int qi = p * 256 + tid;
            int dd = qi >> 4, c8 = (qi & 15) * 8;
            bf16x8 v = *(const bf16x8*)(vt + (((long)(b * 8 + hh) * 64 + dd) << 10) + m0 + c8);
            *(bf16x8*)&Vs[dd][c8] = v;
        }
        __syncthreads();                    // staging visible

        // S^T = K·Q^T: each K-fragment feeds both n-blocks
        f32x4 s[2][8] = {};
        __builtin_amdgcn_s_setprio(1);
#pragma unroll
        for (int ks = 0; ks < 2; ++ks) {
#pragma unroll
            for (int i = 0; i < 8; ++i) {
                bf16x8 ak = *(const bf16x8*)&Ks[i * 16 + l15][ks * 32 + l4 * 8];
                s[0][i] = __builtin_amdgcn_mfma_f32_16x16x32_bf16(ak, bq[0][ks], s[0][i], 0, 0, 0);
                s[1][i] = __builtin_amdgcn_mfma_f32_16x16x32_bf16(ak, bq[1][ks], s[1][i], 0, 0, 0);
            }
        }
        __builtin_amdgcn_s_setprio(0);

        // P = exp2(S * 0.125*log2e), packed to bf16 pairs by HW cvt_pk
        unsigned pk[2][8][2];
#pragma unroll
        for (int nb = 0; nb < 2; ++nb)
#pragma unroll
            for (int i = 0; i < 8; ++i) {
                float e0 = __builtin_amdgcn_exp2f(s[nb][i][0] * EC);
                float e1 = __builtin_amdgcn_exp2f(s[nb][i][1] * EC);
                float e2 = __builtin_amdgcn_exp2f(s[nb][i][2] * EC);
                float e3 = __builtin_amdgcn_exp2f(s[nb][i][3] * EC);
                asm("v_cvt_pk_bf16_f32 %0, %1, %2" : "=v"(pk[nb][i][0]) : "v"(e0), "v"(e1));
                asm("v_cvt_pk_bf16_f32 %0, %1, %2" : "=v"(pk[nb][i][1]) : "v"(e2), "v"(e3));
            }

        // O += P·V ; l += P·1  (permuted k-slots: slot (l4,j) carries
        // m = (2*mb + (j>>2))*16 + l4*4 + (j&3) — lane's own pk regs = A-frag).
        __builtin_amdgcn_s_setprio(1);
#pragma unroll
        for (int mb = 0; mb < 4; ++mb) {
            union { bf16x8 v8; unsigned long long h[2]; } bfr[4];
#pragma unroll
            for (int db = 0; db < 4; ++db) {
                bfr[db].h[0] = *(const unsigned long long*)&Vs[db * 16 + l15][mb * 32 + l4 * 4];
                bfr[db].h[1] = *(const unsigned long long*)&Vs[db * 16 + l15][mb * 32 + 16 + l4 * 4];
            }
#pragma unroll
            for (int nb = 0; nb < 2; ++nb) {
                union { bf16x8 v8; unsigned u32v[4]; } af;
                af.u32v[0] = pk[nb][2 * mb][0];
                af.u32v[1] = pk[nb][2 * mb][1];
                af.u32v[2] = pk[nb][2 * mb + 1][0];
                af.u32v[3] = pk[nb][2 * mb + 1][1];
                lacc[nb] = __builtin_amdgcn_mfma_f32_16x16x32_bf16(af.v8, ones.v8,
                                                                   lacc[nb], 0, 0, 0);
#pragma unroll
                for (int db = 0; db < 4; ++db)
                    oacc[nb][db] = __builtin_amdgcn_mfma_f32_16x16x32_bf16(af.v8, bfr[db].v8,
                                                                           oacc[nb][db], 0, 0, 0);
            }
        }
        __builtin_amdgcn_s_setprio(0);
    }

    // finalize: O /= l — lacc[nb][r] is l at n = wave*32 + nb*16 + l4*4 + r
#pragma unroll
    for (int nb = 0; nb < 2; ++nb)
#pragma unroll
        for (int r = 0; r < 4; ++r) {
            float inv = 1.f / lacc[nb][r];
            int n = wave * 32 + nb * 16 + l4 * 4 + r;
#pragma unroll
            for (int db = 0; db < 4; ++db) {
                int dd = db * 16 + l15;
                o[((long)(b * 4096 + n0 + n)) * 512 + hh * 64 + dd] = f2bf(oacc[nb][db][r] * inv);
            }
        }
}

extern "C" void kernel_launch(void* const* d_in, const int* in_sizes, int n_in,
                              void* d_out, int out_size, void* d_ws, size_t ws_size,
                              hipStream_t stream) {
    const float* x    = (const float*)d_in[0];
    const float* ctx  = (const float*)d_in[1];
    const float* Wq   = (const float*)d_in[2];
    const float* bq   = (const float*)d_in[3];
    const float* Wk   = (const float*)d_in[4];
    const float* bk   = (const float*)d_in[5];
    const float* Wv   = (const float*)d_in[6];
    const float* bv   = (const float*)d_in[7];
    const float* Wp   = (const float*)d_in[8];
    const float* bp   = (const float*)d_in[9];
    const float* Wsrk = (const float*)d_in[10];
    const float* bsrk = (const float*)d_in[11];
    const float* Wsrv = (const float*)d_in[12];
    const float* bsrv = (const float*)d_in[13];
    const float* gk   = (const float*)d_in[14];
    const float* bek  = (const float*)d_in[15];
    const float* gv   = (const float*)d_in[16];
    const float* bev  = (const float*)d_in[17];

    // workspace layout (elems of bf16)
    ushort_t* x_bf    = (ushort_t*)d_ws;
    ushort_t* ctx_bf  = x_bf    + 16777216;
    ushort_t* q_bf    = ctx_bf  + 16777216;
    ushort_t* at_bf   = q_bf    + 16777216;
    ushort_t* k_bf    = at_bf   + 16777216;
    ushort_t* vt_bf   = k_bf    + 4194304;
    ushort_t* convk   = vt_bf   + 4194304;   // LN in-place -> ctx_k
    ushort_t* convv   = convk   + 4194304;   // LN in-place -> ctx_v (contiguous!)
    ushort_t* wq_bf   = convv   + 4194304;   // wq..wp contiguous (cast_w4)
    ushort_t* wk_bf   = wq_bf   + 262144;
    ushort_t* wv_bf   = wk_bf   + 262144;
    ushort_t* wp_bf   = wv_bf   + 262144;
    ushort_t* wsrk_p  = wp_bf   + 262144;    // wsrk_p||wsrv_p contiguous (pack_wsr2)
    ushort_t* wsrv_p  = wsrk_p  + 1048576;

    // 1) casts + weight packing (4 dispatches)
    cast_bf16_kernel<<<8192, 256, 0, stream>>>(x,   x_bf,   16777216);
    cast_bf16_kernel<<<8192, 256, 0, stream>>>(ctx, ctx_bf, 16777216);
    cast_w4_kernel<<<512, 256, 0, stream>>>(Wq, Wk, Wv, Wp, wq_bf);
    pack_wsr2_kernel<<<8192, 256, 0, stream>>>(Wsrk, Wsrv, wsrk_p);

    // 2) both SR convs as one dual-job gathered GEMM (512 blocks -> 2/CU)
    GemmJob jck = { ctx_bf, wsrk_p, bsrk, convk, 0 };
    GemmJob jcv = { ctx_bf, wsrv_p, bsrv, convv, 0 };
    gemm_bt<true><<<dim3(4, 64, 2), 256, 0, stream>>>(jck, jcv, 8192, 512, 2048);

    // 3) both LayerNorms in one dispatch (convk||convv contiguous)
    ln_kernel<<<4096, 256, 0, stream>>>(convk, gk, bek, gv, bev);

    // 4) projections: q alone (1024 blocks), k+v as dual-job (512 blocks)
    GemmJob jq  = { x_bf,  wq_bf, bq, q_bf, 0 };
    gemm_bt<false><<<dim3(4, 256, 1), 256, 0, stream>>>(jq, jq, 32768, 512, 512);
    GemmJob jk  = { convk, wk_bf, bk, k_bf, 0 };
    GemmJob jv  = { convv, wv_bf, bv, vt_bf, 2 };
    gemm_bt<false><<<dim3(4, 64, 2), 256, 0, stream>>>(jk, jv, 8192, 512, 512);

    // 5) attention: 128 q-rows/block, 2 n-blocks/wave (R1-exact)
    attn_kernel<<<dim3(32, 8, 8), 256, 0, stream>>>(q_bf, k_bf, vt_bf, at_bf);

    // 6) output projection -> fp32 d_out
    GemmJob jo  = { at_bf, wp_bf, bp, d_out, 1 };
    gemm_bt<false><<<dim3(4, 256, 1), 256, 0, stream>>>(jo, jo, 32768, 512, 512);
}

// Round 5
// 454.195 us; speedup vs baseline: 1.0534x; 1.0534x over previous
//
#include <hip/hip_runtime.h>
#include <hip/hip_bf16.h>

typedef float f32x4 __attribute__((ext_vector_type(4)));
typedef short bf16x8 __attribute__((ext_vector_type(8)));
typedef unsigned short ushort_t;

// ---------- bf16 helpers (RNE) ----------
__device__ __forceinline__ ushort_t f2bf(float f) {
    union { float f; unsigned u; } v; v.f = f;
    unsigned r = v.u + 0x7fffu + ((v.u >> 16) & 1u);
    return (ushort_t)(r >> 16);
}
__device__ __forceinline__ float bf2f(ushort_t h) {
    union { unsigned u; float f; } v; v.u = ((unsigned)h) << 16;
    return v.f;
}

// ---------- async global->LDS 16B/lane (wave-uniform LDS base + lane*16) ----------
__device__ __forceinline__ void async16(ushort_t* lds, const ushort_t* g) {
    __builtin_amdgcn_global_load_lds(
        (const __attribute__((address_space(1))) unsigned int*)g,
        (__attribute__((address_space(3))) unsigned int*)lds, 16, 0, 0);
}

// ---------- cast fp32 -> bf16, 8 elems/thread ----------
__global__ __launch_bounds__(256) void cast_bf16_kernel(const float* __restrict__ src,
                                                        ushort_t* __restrict__ dst, long n) {
    long i = ((long)blockIdx.x * 256 + threadIdx.x) * 8;
    if (i >= n) return;
    float4 a = *(const float4*)(src + i);
    float4 b = *(const float4*)(src + i + 4);
    ushort_t o[8];
    o[0]=f2bf(a.x); o[1]=f2bf(a.y); o[2]=f2bf(a.z); o[3]=f2bf(a.w);
    o[4]=f2bf(b.x); o[5]=f2bf(b.y); o[6]=f2bf(b.z); o[7]=f2bf(b.w);
    *(bf16x8*)(dst + i) = *(bf16x8*)o;
}

// ---------- cast 4 weight matrices (each 512x512) in one dispatch ----------
__global__ __launch_bounds__(256) void cast_w4_kernel(const float* __restrict__ s0,
                                                      const float* __restrict__ s1,
                                                      const float* __restrict__ s2,
                                                      const float* __restrict__ s3,
                                                      ushort_t* __restrict__ dst) {
    long idx = (long)blockIdx.x * 256 + threadIdx.x;          // 131072 threads
    int sel = (int)(idx >> 15);
    const float* s = sel == 0 ? s0 : sel == 1 ? s1 : sel == 2 ? s2 : s3;
    long off = (idx & 32767) * 8;
    float4 a = *(const float4*)(s + off);
    float4 b = *(const float4*)(s + off + 4);
    ushort_t o[8];
    o[0]=f2bf(a.x); o[1]=f2bf(a.y); o[2]=f2bf(a.z); o[3]=f2bf(a.w);
    o[4]=f2bf(b.x); o[5]=f2bf(b.y); o[6]=f2bf(b.z); o[7]=f2bf(b.w);
    *(bf16x8*)(dst + (long)sel * 262144 + off) = *(bf16x8*)o;
}

// ---------- pack both Wsr [C,C,2,2] -> bf16 B^T layout [c][tap*512+ci] ----------
// float4 read (coalesced, all 4 taps of one (c,ci)) + 4 coalesced tap-segment
// writes. Removes the previous stride-4 scalar gather's 4x read over-fetch.
__global__ __launch_bounds__(256) void pack_wsr2_kernel(const float* __restrict__ w0,
                                                        const float* __restrict__ w1,
                                                        ushort_t* __restrict__ out) {
    int idx = blockIdx.x * 256 + threadIdx.x;   // 524288 total
    int sel = idx >> 18;
    const float* w = sel ? w1 : w0;
    int li = idx & 262143;
    int c = li >> 9, ci = li & 511;
    float4 t = *(const float4*)(w + c * 2048 + ci * 4);   // taps (kh,kw) = elems 0..3
    ushort_t* ob = out + sel * 1048576 + c * 2048 + ci;
    ob[0]    = f2bf(t.x);
    ob[512]  = f2bf(t.y);
    ob[1024] = f2bf(t.z);
    ob[1536] = f2bf(t.w);
}

// ---------- multi-job 128x128 bf16 MFMA GEMM: C = A[M,K] * B[512,K]^T + bias ----------
// Up to three jobs with per-job {M, K, gather} packed into one flat-grid dispatch
// so independent GEMMs backfill the machine (conv 512 blocks alone = 2/CU idle-heavy).
// Blocks [0,nb0) -> j0, [nb0,nb0+nb1) -> j1, rest -> j2. Critical-path jobs first.
// Staging via global_load_lds width=16; LDS LINEAR [128][64] (gload_lds contract).
// omode 0: bf16 out [M,512]; 1: fp32 out; 2: bf16 transposed vT[B,8,64,1024].
struct GemmJob {
    const ushort_t* A;
    const ushort_t* Bw;
    const float* bias;
    void* C;
    int omode;
    int M;
    int K;
    int gather;
};

__global__ __launch_bounds__(256) void gemm_multi(GemmJob j0, GemmJob j1, GemmJob j2,
                                                  int nb0, int nb1) {
    __shared__ __align__(16) ushort_t As[128][64];
    __shared__ __align__(16) ushort_t Bs[128][64];
    const int bid = blockIdx.x;
    GemmJob j;
    int local;
    if (bid < nb0)            { j = j0; local = bid; }
    else if (bid < nb0 + nb1) { j = j1; local = bid - nb0; }
    else                      { j = j2; local = bid - nb0 - nb1; }

    const int tid  = threadIdx.x;
    const int row0 = (local >> 2) * 128, col0 = (local & 3) * 128;  // N=512 -> 4 col-blocks
    const int wave = tid >> 6, lane = tid & 63;
    const int rw = wave >> 1, cw = wave & 1;
    const int l15 = lane & 15, l4 = lane >> 4;
    const int srow = wave * 8 + (lane >> 3);     // staging row within 32-row group
    const int sc8  = (lane & 7) * 8;             // staging col (elems)
    const int K = j.K;

    f32x4 acc[4][4] = {};

    for (int k0 = 0; k0 < K; k0 += 64) {
        __syncthreads();                         // prev tile's reads done
#pragma unroll
        for (int p = 0; p < 4; ++p) {
            int r = p * 32 + srow;
            const ushort_t* ga;
            if (j.gather) {
                int gr = row0 + r;
                int b = gr >> 10, m = gr & 1023;
                int mh = m >> 5, mw = m & 31;
                int tap = k0 >> 9;
                int kh = tap >> 1, kw = tap & 1;
                ga = j.A + ((long)(b * 4096 + (2 * mh + kh) * 64 + (2 * mw + kw))) * 512
                         + (k0 & 511) + sc8;
            } else {
                ga = j.A + (long)(row0 + r) * K + k0 + sc8;
            }
            async16(&As[p * 32 + wave * 8][0], ga);
            async16(&Bs[p * 32 + wave * 8][0],
                    j.Bw + (long)(col0 + r) * K + k0 + sc8);
        }
        __syncthreads();                         // vmcnt(0) drained by compiler
#pragma unroll
        for (int ks = 0; ks < 2; ++ks) {
            bf16x8 af[4], bfr[4];
#pragma unroll
            for (int i = 0; i < 4; ++i)
                af[i] = *(const bf16x8*)&As[rw * 64 + i * 16 + l15][ks * 32 + l4 * 8];
#pragma unroll
            for (int jj = 0; jj < 4; ++jj)
                bfr[jj] = *(const bf16x8*)&Bs[cw * 64 + jj * 16 + l15][ks * 32 + l4 * 8];
#pragma unroll
            for (int i = 0; i < 4; ++i)
#pragma unroll
                for (int jj = 0; jj < 4; ++jj)
                    acc[i][jj] = __builtin_amdgcn_mfma_f32_16x16x32_bf16(af[i], bfr[jj],
                                                                         acc[i][jj], 0, 0, 0);
        }
    }
    // epilogue: C/D layout col=lane&15, row=(lane>>4)*4+reg  [m89-verified]
#pragma unroll
    for (int i = 0; i < 4; ++i) {
#pragma unroll
        for (int jj = 0; jj < 4; ++jj) {
            int col = col0 + cw * 64 + jj * 16 + l15;
            float bv = j.bias[col];
#pragma unroll
            for (int r = 0; r < 4; ++r) {
                int row = row0 + rw * 64 + i * 16 + l4 * 4 + r;
                float v = acc[i][jj][r] + bv;
                if (j.omode == 0) {
                    ((ushort_t*)j.C)[(long)row * 512 + col] = f2bf(v);
                } else if (j.omode == 1) {
                    ((float*)j.C)[(long)row * 512 + col] = v;
                } else {
                    int b = row >> 10, m = row & 1023;
                    int hh = col >> 6, dd = col & 63;
                    ((ushort_t*)j.C)[(((long)(b * 8 + hh) * 64 + dd) << 10) + m] = f2bf(v);
                }
            }
        }
    }
}

// ---------- in-place LayerNorm over rows of 512 (bf16), wave per row ----------
// rows 0..8191 use (g0,be0); rows 8192..16383 use (g1,be1)  (convk||convv contiguous)
__global__ __launch_bounds__(256) void ln_kernel(ushort_t* __restrict__ data,
                                                 const float* __restrict__ g0,
                                                 const float* __restrict__ be0,
                                                 const float* __restrict__ g1,
                                                 const float* __restrict__ be1) {
    int wave = threadIdx.x >> 6, lane = threadIdx.x & 63;
    long row = (long)blockIdx.x * 4 + wave;
    const float* g  = row < 8192 ? g0 : g1;
    const float* be = row < 8192 ? be0 : be1;
    ushort_t* p = data + row * 512 + lane * 8;
    bf16x8 raw = *(bf16x8*)p;
    ushort_t* rp = (ushort_t*)&raw;
    float v[8], s = 0.f, s2 = 0.f;
#pragma unroll
    for (int j = 0; j < 8; ++j) { v[j] = bf2f(rp[j]); s += v[j]; s2 += v[j] * v[j]; }
#pragma unroll
    for (int d = 1; d < 64; d <<= 1) { s += __shfl_xor(s, d); s2 += __shfl_xor(s2, d); }
    float mu  = s * (1.f / 512.f);
    float var = s2 * (1.f / 512.f) - mu * mu;
    float rs  = rsqrtf(var + 1e-5f);
    ushort_t o[8];
#pragma unroll
    for (int j = 0; j < 8; ++j) {
        int c = lane * 8 + j;
        o[j] = f2bf((v[j] - mu) * rs * g[c] + be[c]);
    }
    *(bf16x8*)p = *(bf16x8*)o;
}

// ---------- flash attention v5 (R1-exact, synchronous staging — PASSED) ----------
// Block = (b, head, 128 q-rows); wave owns 32 q-rows (2 n-blocks), sharing each
// K-fragment and V-fragment across both. Q fragments in registers.
// P = exp2(S * 0.125*log2e), packed by HW v_cvt_pk_bf16_f32.
// l = sum_m P via extra MFMA with ones-B.
// NOTE: T14 async-split staging FAILED here (absmax 0.13, R2) — do not re-add
// without asm-level verification of the wait placement.
__global__ __launch_bounds__(256, 3) void attn_kernel(const ushort_t* __restrict__ q,
                                                      const ushort_t* __restrict__ k,
                                                      const ushort_t* __restrict__ vt,
                                                      ushort_t* __restrict__ o) {
    __shared__ __align__(16) ushort_t Ks[128][72];
    __shared__ __align__(16) ushort_t Vs[64][136];   // V^T: [d][m]

    const int tid = threadIdx.x;
    const int wave = tid >> 6, lane = tid & 63;
    const int l15 = lane & 15, l4 = lane >> 4;
    const int n0 = blockIdx.x * 128;
    const int hh = blockIdx.y;
    const int b  = blockIdx.z;

    // Q fragments: wave's q-rows are n0 + wave*32 + nb*16 + l15 (unscaled bf16)
    bf16x8 bq[2][2];
#pragma unroll
    for (int nb = 0; nb < 2; ++nb)
#pragma unroll
        for (int ks = 0; ks < 2; ++ks)
            bq[nb][ks] = *(const bf16x8*)(
                q + (long)(b * 4096 + n0 + wave * 32 + nb * 16 + l15) * 512
                  + hh * 64 + ks * 32 + l4 * 8);

    f32x4 oacc[2][4] = {};
    f32x4 lacc[2] = {};
    union { bf16x8 v8; unsigned u[4]; } ones;
    ones.u[0] = ones.u[1] = ones.u[2] = ones.u[3] = 0x3F803F80u;
    const float EC = 0.18033688011112042f;   // 0.125 * log2(e)

    for (int c = 0; c < 8; ++c) {
        const int m0 = c * 128;
        __syncthreads();                    // previous chunk's LDS reads done
#pragma unroll
        for (int p = 0; p < 4; ++p) {       // K chunk [128 m][64 d]
            int qi = p * 256 + tid;
            int r = qi >> 3, c8 = (qi & 7) * 8;
            bf16x8 v = *(const bf16x8*)(k + (((long)(b * 1024 + m0 + r) * 8 + hh) << 6) + c8);
            *(bf16x8*)&Ks[r][c8] = v;
        }
#pragma unroll
        for (int p = 0; p < 4; ++p) {       // V^T chunk [64 d][128 m]
            int qi = p * 256 + tid;
            int dd = qi >> 4, c8 = (qi & 15) * 8;
            bf16x8 v = *(const bf16x8*)(vt + (((long)(b * 8 + hh) * 64 + dd) << 10) + m0 + c8);
            *(bf16x8*)&Vs[dd][c8] = v;
        }
        __syncthreads();                    // staging visible

        // S^T = K·Q^T: each K-fragment feeds both n-blocks
        f32x4 s[2][8] = {};
        __builtin_amdgcn_s_setprio(1);
#pragma unroll
        for (int ks = 0; ks < 2; ++ks) {
#pragma unroll
            for (int i = 0; i < 8; ++i) {
                bf16x8 ak = *(const bf16x8*)&Ks[i * 16 + l15][ks * 32 + l4 * 8];
                s[0][i] = __builtin_amdgcn_mfma_f32_16x16x32_bf16(ak, bq[0][ks], s[0][i], 0, 0, 0);
                s[1][i] = __builtin_amdgcn_mfma_f32_16x16x32_bf16(ak, bq[1][ks], s[1][i], 0, 0, 0);
            }
        }
        __builtin_amdgcn_s_setprio(0);

        // P = exp2(S * 0.125*log2e), packed to bf16 pairs by HW cvt_pk
        unsigned pk[2][8][2];
#pragma unroll
        for (int nb = 0; nb < 2; ++nb)
#pragma unroll
            for (int i = 0; i < 8; ++i) {
                float e0 = __builtin_amdgcn_exp2f(s[nb][i][0] * EC);
                float e1 = __builtin_amdgcn_exp2f(s[nb][i][1] * EC);
                float e2 = __builtin_amdgcn_exp2f(s[nb][i][2] * EC);
                float e3 = __builtin_amdgcn_exp2f(s[nb][i][3] * EC);
                asm("v_cvt_pk_bf16_f32 %0, %1, %2" : "=v"(pk[nb][i][0]) : "v"(e0), "v"(e1));
                asm("v_cvt_pk_bf16_f32 %0, %1, %2" : "=v"(pk[nb][i][1]) : "v"(e2), "v"(e3));
            }

        // O += P·V ; l += P·1  (permuted k-slots: slot (l4,j) carries
        // m = (2*mb + (j>>2))*16 + l4*4 + (j&3) — lane's own pk regs = A-frag).
        __builtin_amdgcn_s_setprio(1);
#pragma unroll
        for (int mb = 0; mb < 4; ++mb) {
            union { bf16x8 v8; unsigned long long h[2]; } bfr[4];
#pragma unroll
            for (int db = 0; db < 4; ++db) {
                bfr[db].h[0] = *(const unsigned long long*)&Vs[db * 16 + l15][mb * 32 + l4 * 4];
                bfr[db].h[1] = *(const unsigned long long*)&Vs[db * 16 + l15][mb * 32 + 16 + l4 * 4];
            }
#pragma unroll
            for (int nb = 0; nb < 2; ++nb) {
                union { bf16x8 v8; unsigned u32v[4]; } af;
                af.u32v[0] = pk[nb][2 * mb][0];
                af.u32v[1] = pk[nb][2 * mb][1];
                af.u32v[2] = pk[nb][2 * mb + 1][0];
                af.u32v[3] = pk[nb][2 * mb + 1][1];
                lacc[nb] = __builtin_amdgcn_mfma_f32_16x16x32_bf16(af.v8, ones.v8,
                                                                   lacc[nb], 0, 0, 0);
#pragma unroll
                for (int db = 0; db < 4; ++db)
                    oacc[nb][db] = __builtin_amdgcn_mfma_f32_16x16x32_bf16(af.v8, bfr[db].v8,
                                                                           oacc[nb][db], 0, 0, 0);
            }
        }
        __builtin_amdgcn_s_setprio(0);
    }

    // finalize: O /= l — lacc[nb][r] is l at n = wave*32 + nb*16 + l4*4 + r
#pragma unroll
    for (int nb = 0; nb < 2; ++nb)
#pragma unroll
        for (int r = 0; r < 4; ++r) {
            float inv = 1.f / lacc[nb][r];
            int n = wave * 32 + nb * 16 + l4 * 4 + r;
#pragma unroll
            for (int db = 0; db < 4; ++db) {
                int dd = db * 16 + l15;
                o[((long)(b * 4096 + n0 + n)) * 512 + hh * 64 + dd] = f2bf(oacc[nb][db][r] * inv);
            }
        }
}

extern "C" void kernel_launch(void* const* d_in, const int* in_sizes, int n_in,
                              void* d_out, int out_size, void* d_ws, size_t ws_size,
                              hipStream_t stream) {
    const float* x    = (const float*)d_in[0];
    const float* ctx  = (const float*)d_in[1];
    const float* Wq   = (const float*)d_in[2];
    const float* bq   = (const float*)d_in[3];
    const float* Wk   = (const float*)d_in[4];
    const float* bk   = (const float*)d_in[5];
    const float* Wv   = (const float*)d_in[6];
    const float* bv   = (const float*)d_in[7];
    const float* Wp   = (const float*)d_in[8];
    const float* bp   = (const float*)d_in[9];
    const float* Wsrk = (const float*)d_in[10];
    const float* bsrk = (const float*)d_in[11];
    const float* Wsrv = (const float*)d_in[12];
    const float* bsrv = (const float*)d_in[13];
    const float* gk   = (const float*)d_in[14];
    const float* bek  = (const float*)d_in[15];
    const float* gv   = (const float*)d_in[16];
    const float* bev  = (const float*)d_in[17];

    // workspace layout (elems of bf16)
    ushort_t* x_bf    = (ushort_t*)d_ws;
    ushort_t* ctx_bf  = x_bf    + 16777216;
    ushort_t* q_bf    = ctx_bf  + 16777216;
    ushort_t* at_bf   = q_bf    + 16777216;
    ushort_t* k_bf    = at_bf   + 16777216;
    ushort_t* vt_bf   = k_bf    + 4194304;
    ushort_t* convk   = vt_bf   + 4194304;   // LN in-place -> ctx_k
    ushort_t* convv   = convk   + 4194304;   // LN in-place -> ctx_v (contiguous!)
    ushort_t* wq_bf   = convv   + 4194304;   // wq..wp contiguous (cast_w4)
    ushort_t* wk_bf   = wq_bf   + 262144;
    ushort_t* wv_bf   = wk_bf   + 262144;
    ushort_t* wp_bf   = wv_bf   + 262144;
    ushort_t* wsrk_p  = wp_bf   + 262144;    // wsrk_p||wsrv_p contiguous (pack_wsr2)
    ushort_t* wsrv_p  = wsrk_p  + 1048576;

    // 1) casts + weight packing (4 dispatches)
    cast_bf16_kernel<<<8192, 256, 0, stream>>>(x,   x_bf,   16777216);
    cast_bf16_kernel<<<8192, 256, 0, stream>>>(ctx, ctx_bf, 16777216);
    cast_w4_kernel<<<512, 256, 0, stream>>>(Wq, Wk, Wv, Wp, wq_bf);
    pack_wsr2_kernel<<<2048, 256, 0, stream>>>(Wsrk, Wsrv, wsrk_p);

    // 2) MERGED: conv-k + conv-v (gather, K=2048, critical path first) + q-proj
    //    (K=512, independent) in one 1536-block dispatch — q backfills conv's tail.
    GemmJob jck = { ctx_bf, wsrk_p, bsrk, convk, 0, 8192,  2048, 1 };
    GemmJob jcv = { ctx_bf, wsrv_p, bsrv, convv, 0, 8192,  2048, 1 };
    GemmJob jq  = { x_bf,  wq_bf,  bq,   q_bf,  0, 32768, 512,  0 };
    gemm_multi<<<1536, 256, 0, stream>>>(jck, jcv, jq, 256, 256);

    // 3) both LayerNorms in one dispatch (convk||convv contiguous)
    ln_kernel<<<4096, 256, 0, stream>>>(convk, gk, bek, gv, bev);

    // 4) k+v projections as dual-job (512 blocks)
    GemmJob jk  = { convk, wk_bf, bk, k_bf,  0, 8192, 512, 0 };
    GemmJob jv  = { convv, wv_bf, bv, vt_bf, 2, 8192, 512, 0 };
    gemm_multi<<<512, 256, 0, stream>>>(jk, jv, jv, 256, 256);

    // 5) attention: 128 q-rows/block, 2 n-blocks/wave (R1-exact, known-good)
    attn_kernel<<<dim3(32, 8, 8), 256, 0, stream>>>(q_bf, k_bf, vt_bf, at_bf);

    // 6) output projection -> fp32 d_out
    GemmJob jo  = { at_bf, wp_bf, bp, d_out, 1, 32768, 512, 0 };
    gemm_multi<<<1024, 256, 0, stream>>>(jo, jo, jo, 1024, 0);
}

// Round 7
// 435.303 us; speedup vs baseline: 1.0991x; 1.0434x over previous
//
#include <hip/hip_runtime.h>
#include <hip/hip_bf16.h>

typedef float f32x4 __attribute__((ext_vector_type(4)));
typedef short bf16x8 __attribute__((ext_vector_type(8)));
typedef unsigned short ushort_t;

// ---------- bf16 helpers (RNE) ----------
__device__ __forceinline__ ushort_t f2bf(float f) {
    union { float f; unsigned u; } v; v.f = f;
    unsigned r = v.u + 0x7fffu + ((v.u >> 16) & 1u);
    return (ushort_t)(r >> 16);
}
__device__ __forceinline__ float bf2f(ushort_t h) {
    union { unsigned u; float f; } v; v.u = ((unsigned)h) << 16;
    return v.f;
}

// ---------- async global->LDS 16B/lane (wave-uniform LDS base + lane*16) ----------
__device__ __forceinline__ void async16(ushort_t* lds, const ushort_t* g) {
    __builtin_amdgcn_global_load_lds(
        (const __attribute__((address_space(1))) unsigned int*)g,
        (__attribute__((address_space(3))) unsigned int*)lds, 16, 0, 0);
}

// ---------- cast fp32 -> bf16: both inputs (x then ctx) in ONE dispatch ----------
// dst is contiguous: x_bf || ctx_bf. blocks 0..8191 -> src0, 8192..16383 -> src1.
__global__ __launch_bounds__(256) void cast2_bf16_kernel(const float* __restrict__ s0,
                                                         const float* __restrict__ s1,
                                                         ushort_t* __restrict__ dst) {
    long idx = (long)blockIdx.x * 256 + threadIdx.x;   // 4194304 threads
    int sel = (int)(idx >> 21);
    const float* s = sel ? s1 : s0;
    long off = (idx & 2097151) * 8;
    float4 a = *(const float4*)(s + off);
    float4 b = *(const float4*)(s + off + 4);
    ushort_t o[8];
    o[0]=f2bf(a.x); o[1]=f2bf(a.y); o[2]=f2bf(a.z); o[3]=f2bf(a.w);
    o[4]=f2bf(b.x); o[5]=f2bf(b.y); o[6]=f2bf(b.z); o[7]=f2bf(b.w);
    *(bf16x8*)(dst + (long)sel * 16777216 + off) = *(bf16x8*)o;
}

// ---------- cast 4 weight matrices (each 512x512) in one dispatch ----------
__global__ __launch_bounds__(256) void cast_w4_kernel(const float* __restrict__ s0,
                                                      const float* __restrict__ s1,
                                                      const float* __restrict__ s2,
                                                      const float* __restrict__ s3,
                                                      ushort_t* __restrict__ dst) {
    long idx = (long)blockIdx.x * 256 + threadIdx.x;          // 131072 threads
    int sel = (int)(idx >> 15);
    const float* s = sel == 0 ? s0 : sel == 1 ? s1 : sel == 2 ? s2 : s3;
    long off = (idx & 32767) * 8;
    float4 a = *(const float4*)(s + off);
    float4 b = *(const float4*)(s + off + 4);
    ushort_t o[8];
    o[0]=f2bf(a.x); o[1]=f2bf(a.y); o[2]=f2bf(a.z); o[3]=f2bf(a.w);
    o[4]=f2bf(b.x); o[5]=f2bf(b.y); o[6]=f2bf(b.z); o[7]=f2bf(b.w);
    *(bf16x8*)(dst + (long)sel * 262144 + off) = *(bf16x8*)o;
}

// ---------- pack both Wsr [C,C,2,2] -> bf16 B^T layout [c][tap*512+ci] ----------
// float4 read (coalesced, all 4 taps of one (c,ci)) + 4 coalesced tap-segment writes.
__global__ __launch_bounds__(256) void pack_wsr2_kernel(const float* __restrict__ w0,
                                                        const float* __restrict__ w1,
                                                        ushort_t* __restrict__ out) {
    int idx = blockIdx.x * 256 + threadIdx.x;   // 524288 total
    int sel = idx >> 18;
    const float* w = sel ? w1 : w0;
    int li = idx & 262143;
    int c = li >> 9, ci = li & 511;
    float4 t = *(const float4*)(w + c * 2048 + ci * 4);   // taps (kh,kw) = elems 0..3
    ushort_t* ob = out + sel * 1048576 + c * 2048 + ci;
    ob[0]    = f2bf(t.x);
    ob[512]  = f2bf(t.y);
    ob[1024] = f2bf(t.z);
    ob[1536] = f2bf(t.w);
}

// ---------- multi-job 128x128 bf16 MFMA GEMM: C = (A[M,K] * B[512,K]^T + bias)*oscale ----
// Up to three jobs {M,K,gather,oscale} in one flat-grid dispatch (backfill idle CUs).
// XCD-grouped decode: the 4 col-blocks sharing a row-panel get bids differing by
// 8/16/24 -> same XCD (bid%8 round-robin, m09/T1) -> A-panel fetched from HBM once,
// L2-hits for the other 3 (was 4x HBM re-fetch with consecutive-bid decode).
// Requires nb multiple of 32 (all ours are 256/512/1024). Bijective.
// Staging via global_load_lds width=16; LDS LINEAR [128][64] (gload_lds contract).
// omode 0: bf16 out [M,512]; 1: fp32 out; 2: bf16 transposed vT[B,8,64,1024].
struct GemmJob {
    const ushort_t* A;
    const ushort_t* Bw;
    const float* bias;
    void* C;
    int omode;
    int M;
    int K;
    int gather;
    float oscale;
};

__global__ __launch_bounds__(256) void gemm_multi(GemmJob j0, GemmJob j1, GemmJob j2,
                                                  int nb0, int nb1) {
    __shared__ __align__(16) ushort_t As[128][64];
    __shared__ __align__(16) ushort_t Bs[128][64];
    const int bid = blockIdx.x;
    GemmJob j;
    int local;
    if (bid < nb0)            { j = j0; local = bid; }
    else if (bid < nb0 + nb1) { j = j1; local = bid - nb0; }
    else                      { j = j2; local = bid - nb0 - nb1; }

    const int tid  = threadIdx.x;
    // XCD-grouped decode: row = (local&7) | ((local>>5)<<3), col = (local>>3)&3
    const int row0 = (((local & 7) | ((local >> 5) << 3))) * 128;
    const int col0 = ((local >> 3) & 3) * 128;
    const int wave = tid >> 6, lane = tid & 63;
    const int rw = wave >> 1, cw = wave & 1;
    const int l15 = lane & 15, l4 = lane >> 4;
    const int srow = wave * 8 + (lane >> 3);     // staging row within 32-row group
    const int sc8  = (lane & 7) * 8;             // staging col (elems)
    const int K = j.K;

    f32x4 acc[4][4] = {};

    for (int k0 = 0; k0 < K; k0 += 64) {
        __syncthreads();                         // prev tile's reads done
#pragma unroll
        for (int p = 0; p < 4; ++p) {
            int r = p * 32 + srow;
            const ushort_t* ga;
            if (j.gather) {
                int gr = row0 + r;
                int b = gr >> 10, m = gr & 1023;
                int mh = m >> 5, mw = m & 31;
                int tap = k0 >> 9;
                int kh = tap >> 1, kw = tap & 1;
                ga = j.A + ((long)(b * 4096 + (2 * mh + kh) * 64 + (2 * mw + kw))) * 512
                         + (k0 & 511) + sc8;
            } else {
                ga = j.A + (long)(row0 + r) * K + k0 + sc8;
            }
            async16(&As[p * 32 + wave * 8][0], ga);
            async16(&Bs[p * 32 + wave * 8][0],
                    j.Bw + (long)(col0 + r) * K + k0 + sc8);
        }
        __syncthreads();                         // vmcnt(0) drained by compiler
#pragma unroll
        for (int ks = 0; ks < 2; ++ks) {
            bf16x8 af[4], bfr[4];
#pragma unroll
            for (int i = 0; i < 4; ++i)
                af[i] = *(const bf16x8*)&As[rw * 64 + i * 16 + l15][ks * 32 + l4 * 8];
#pragma unroll
            for (int jj = 0; jj < 4; ++jj)
                bfr[jj] = *(const bf16x8*)&Bs[cw * 64 + jj * 16 + l15][ks * 32 + l4 * 8];
#pragma unroll
            for (int i = 0; i < 4; ++i)
#pragma unroll
                for (int jj = 0; jj < 4; ++jj)
                    acc[i][jj] = __builtin_amdgcn_mfma_f32_16x16x32_bf16(af[i], bfr[jj],
                                                                         acc[i][jj], 0, 0, 0);
        }
    }
    // epilogue: C/D layout col=lane&15, row=(lane>>4)*4+reg  [m89-verified]
#pragma unroll
    for (int i = 0; i < 4; ++i) {
#pragma unroll
        for (int jj = 0; jj < 4; ++jj) {
            int col = col0 + cw * 64 + jj * 16 + l15;
            float bv = j.bias[col];
#pragma unroll
            for (int r = 0; r < 4; ++r) {
                int row = row0 + rw * 64 + i * 16 + l4 * 4 + r;
                float v = (acc[i][jj][r] + bv) * j.oscale;
                if (j.omode == 0) {
                    ((ushort_t*)j.C)[(long)row * 512 + col] = f2bf(v);
                } else if (j.omode == 1) {
                    ((float*)j.C)[(long)row * 512 + col] = v;
                } else {
                    int b = row >> 10, m = row & 1023;
                    int hh = col >> 6, dd = col & 63;
                    ((ushort_t*)j.C)[(((long)(b * 8 + hh) * 64 + dd) << 10) + m] = f2bf(v);
                }
            }
        }
    }
}

// ---------- in-place LayerNorm over rows of 512 (bf16), wave per row ----------
// rows 0..8191 use (g0,be0); rows 8192..16383 use (g1,be1)  (convk||convv contiguous)
__global__ __launch_bounds__(256) void ln_kernel(ushort_t* __restrict__ data,
                                                 const float* __restrict__ g0,
                                                 const float* __restrict__ be0,
                                                 const float* __restrict__ g1,
                                                 const float* __restrict__ be1) {
    int wave = threadIdx.x >> 6, lane = threadIdx.x & 63;
    long row = (long)blockIdx.x * 4 + wave;
    const float* g  = row < 8192 ? g0 : g1;
    const float* be = row < 8192 ? be0 : be1;
    ushort_t* p = data + row * 512 + lane * 8;
    bf16x8 raw = *(bf16x8*)p;
    ushort_t* rp = (ushort_t*)&raw;
    float v[8], s = 0.f, s2 = 0.f;
#pragma unroll
    for (int j = 0; j < 8; ++j) { v[j] = bf2f(rp[j]); s += v[j]; s2 += v[j] * v[j]; }
#pragma unroll
    for (int d = 1; d < 64; d <<= 1) { s += __shfl_xor(s, d); s2 += __shfl_xor(s2, d); }
    float mu  = s * (1.f / 512.f);
    float var = s2 * (1.f / 512.f) - mu * mu;
    float rs  = rsqrtf(var + 1e-5f);
    ushort_t o[8];
#pragma unroll
    for (int j = 0; j < 8; ++j) {
        int c = lane * 8 + j;
        o[j] = f2bf((v[j] - mu) * rs * g[c] + be[c]);
    }
    *(bf16x8*)p = *(bf16x8*)o;
}

// ---------- flash attention v7: v5 structure, Q pre-scaled by EC in q-proj ----------
// Block = (b, head, 128 q-rows); wave owns 32 q-rows (2 n-blocks), sharing each
// K-fragment and V-fragment across both. Q fragments in registers.
// q_bf already holds (x@Wq+bq) * 0.125*log2e  ->  P = exp2(S) DIRECTLY
// (64 fewer v_mul_f32 per thread-chunk vs multiplying S by EC here).
// P packed by HW v_cvt_pk_bf16_f32. l = sum_m P via extra MFMA with ones-B.
// NOTE: T14 async-split staging FAILED here (absmax 0.13, R2) — do not re-add
// without asm-level verification of the wait placement.
__global__ __launch_bounds__(256, 3) void attn_kernel(const ushort_t* __restrict__ q,
                                                      const ushort_t* __restrict__ k,
                                                      const ushort_t* __restrict__ vt,
                                                      ushort_t* __restrict__ o) {
    __shared__ __align__(16) ushort_t Ks[128][72];
    __shared__ __align__(16) ushort_t Vs[64][136];   // V^T: [d][m]

    const int tid = threadIdx.x;
    const int wave = tid >> 6, lane = tid & 63;
    const int l15 = lane & 15, l4 = lane >> 4;
    const int n0 = blockIdx.x * 128;
    const int hh = blockIdx.y;
    const int b  = blockIdx.z;

    // Q fragments: wave's q-rows are n0 + wave*32 + nb*16 + l15 (pre-scaled bf16)
    bf16x8 bq[2][2];
#pragma unroll
    for (int nb = 0; nb < 2; ++nb)
#pragma unroll
        for (int ks = 0; ks < 2; ++ks)
            bq[nb][ks] = *(const bf16x8*)(
                q + (long)(b * 4096 + n0 + wave * 32 + nb * 16 + l15) * 512
                  + hh * 64 + ks * 32 + l4 * 8);

    f32x4 oacc[2][4] = {};
    f32x4 lacc[2] = {};
    union { bf16x8 v8; unsigned u[4]; } ones;
    ones.u[0] = ones.u[1] = ones.u[2] = ones.u[3] = 0x3F803F80u;

    for (int c = 0; c < 8; ++c) {
        const int m0 = c * 128;
        __syncthreads();                    // previous chunk's LDS reads done
#pragma unroll
        for (int p = 0; p < 4; ++p) {       // K chunk [128 m][64 d]
            int qi = p * 256 + tid;
            int r = qi >> 3, c8 = (qi & 7) * 8;
            bf16x8 v = *(const bf16x8*)(k + (((long)(b * 1024 + m0 + r) * 8 + hh) << 6) + c8);
            *(bf16x8*)&Ks[r][c8] = v;
        }
#pragma unroll
        for (int p = 0; p < 4; ++p) {       // V^T chunk [64 d][128 m]
            int qi = p * 256 + tid;
            int dd = qi >> 4, c8 = (qi & 15) * 8;
            bf16x8 v = *(const bf16x8*)(vt + (((long)(b * 8 + hh) * 64 + dd) << 10) + m0 + c8);
            *(bf16x8*)&Vs[dd][c8] = v;
        }
        __syncthreads();                    // staging visible

        // S^T = K·Q^T: each K-fragment feeds both n-blocks
        f32x4 s[2][8] = {};
        __builtin_amdgcn_s_setprio(1);
#pragma unroll
        for (int ks = 0; ks < 2; ++ks) {
#pragma unroll
            for (int i = 0; i < 8; ++i) {
                bf16x8 ak = *(const bf16x8*)&Ks[i * 16 + l15][ks * 32 + l4 * 8];
                s[0][i] = __builtin_amdgcn_mfma_f32_16x16x32_bf16(ak, bq[0][ks], s[0][i], 0, 0, 0);
                s[1][i] = __builtin_amdgcn_mfma_f32_16x16x32_bf16(ak, bq[1][ks], s[1][i], 0, 0, 0);
            }
        }
        __builtin_amdgcn_s_setprio(0);

        // P = exp2(S) (Q pre-scaled), packed to bf16 pairs by HW cvt_pk
        unsigned pk[2][8][2];
#pragma unroll
        for (int nb = 0; nb < 2; ++nb)
#pragma unroll
            for (int i = 0; i < 8; ++i) {
                float e0 = __builtin_amdgcn_exp2f(s[nb][i][0]);
                float e1 = __builtin_amdgcn_exp2f(s[nb][i][1]);
                float e2 = __builtin_amdgcn_exp2f(s[nb][i][2]);
                float e3 = __builtin_amdgcn_exp2f(s[nb][i][3]);
                asm("v_cvt_pk_bf16_f32 %0, %1, %2" : "=v"(pk[nb][i][0]) : "v"(e0), "v"(e1));
                asm("v_cvt_pk_bf16_f32 %0, %1, %2" : "=v"(pk[nb][i][1]) : "v"(e2), "v"(e3));
            }

        // O += P·V ; l += P·1  (permuted k-slots: slot (l4,j) carries
        // m = (2*mb + (j>>2))*16 + l4*4 + (j&3) — lane's own pk regs = A-frag).
        __builtin_amdgcn_s_setprio(1);
#pragma unroll
        for (int mb = 0; mb < 4; ++mb) {
            union { bf16x8 v8; unsigned long long h[2]; } bfr[4];
#pragma unroll
            for (int db = 0; db < 4; ++db) {
                bfr[db].h[0] = *(const unsigned long long*)&Vs[db * 16 + l15][mb * 32 + l4 * 4];
                bfr[db].h[1] = *(const unsigned long long*)&Vs[db * 16 + l15][mb * 32 + 16 + l4 * 4];
            }
#pragma unroll
            for (int nb = 0; nb < 2; ++nb) {
                union { bf16x8 v8; unsigned u32v[4]; } af;
                af.u32v[0] = pk[nb][2 * mb][0];
                af.u32v[1] = pk[nb][2 * mb][1];
                af.u32v[2] = pk[nb][2 * mb + 1][0];
                af.u32v[3] = pk[nb][2 * mb + 1][1];
                lacc[nb] = __builtin_amdgcn_mfma_f32_16x16x32_bf16(af.v8, ones.v8,
                                                                   lacc[nb], 0, 0, 0);
#pragma unroll
                for (int db = 0; db < 4; ++db)
                    oacc[nb][db] = __builtin_amdgcn_mfma_f32_16x16x32_bf16(af.v8, bfr[db].v8,
                                                                           oacc[nb][db], 0, 0, 0);
            }
        }
        __builtin_amdgcn_s_setprio(0);
    }

    // finalize: O /= l — lacc[nb][r] is l at n = wave*32 + nb*16 + l4*4 + r
#pragma unroll
    for (int nb = 0; nb < 2; ++nb)
#pragma unroll
        for (int r = 0; r < 4; ++r) {
            float inv = 1.f / lacc[nb][r];
            int n = wave * 32 + nb * 16 + l4 * 4 + r;
#pragma unroll
            for (int db = 0; db < 4; ++db) {
                int dd = db * 16 + l15;
                o[((long)(b * 4096 + n0 + n)) * 512 + hh * 64 + dd] = f2bf(oacc[nb][db][r] * inv);
            }
        }
}

extern "C" void kernel_launch(void* const* d_in, const int* in_sizes, int n_in,
                              void* d_out, int out_size, void* d_ws, size_t ws_size,
                              hipStream_t stream) {
    const float* x    = (const float*)d_in[0];
    const float* ctx  = (const float*)d_in[1];
    const float* Wq   = (const float*)d_in[2];
    const float* bq   = (const float*)d_in[3];
    const float* Wk   = (const float*)d_in[4];
    const float* bk   = (const float*)d_in[5];
    const float* Wv   = (const float*)d_in[6];
    const float* bv   = (const float*)d_in[7];
    const float* Wp   = (const float*)d_in[8];
    const float* bp   = (const float*)d_in[9];
    const float* Wsrk = (const float*)d_in[10];
    const float* bsrk = (const float*)d_in[11];
    const float* Wsrv = (const float*)d_in[12];
    const float* bsrv = (const float*)d_in[13];
    const float* gk   = (const float*)d_in[14];
    const float* bek  = (const float*)d_in[15];
    const float* gv   = (const float*)d_in[16];
    const float* bev  = (const float*)d_in[17];

    // workspace layout (elems of bf16)
    ushort_t* x_bf    = (ushort_t*)d_ws;
    ushort_t* ctx_bf  = x_bf    + 16777216;   // contiguous after x_bf (cast2)
    ushort_t* q_bf    = ctx_bf  + 16777216;
    ushort_t* at_bf   = q_bf    + 16777216;
    ushort_t* k_bf    = at_bf   + 16777216;
    ushort_t* vt_bf   = k_bf    + 4194304;
    ushort_t* convk   = vt_bf   + 4194304;   // LN in-place -> ctx_k
    ushort_t* convv   = convk   + 4194304;   // LN in-place -> ctx_v (contiguous!)
    ushort_t* wq_bf   = convv   + 4194304;   // wq..wp contiguous (cast_w4)
    ushort_t* wk_bf   = wq_bf   + 262144;
    ushort_t* wv_bf   = wk_bf   + 262144;
    ushort_t* wp_bf   = wv_bf   + 262144;
    ushort_t* wsrk_p  = wp_bf   + 262144;    // wsrk_p||wsrv_p contiguous (pack_wsr2)
    ushort_t* wsrv_p  = wsrk_p  + 1048576;

    const float EC = 0.18033688011112042f;   // 0.125 * log2(e), folded into q-proj

    // 1) casts + weight packing (3 dispatches)
    cast2_bf16_kernel<<<16384, 256, 0, stream>>>(x, ctx, x_bf);
    cast_w4_kernel<<<512, 256, 0, stream>>>(Wq, Wk, Wv, Wp, wq_bf);
    pack_wsr2_kernel<<<2048, 256, 0, stream>>>(Wsrk, Wsrv, wsrk_p);

    // 2) MERGED: conv-k + conv-v (gather, K=2048, critical path first) + q-proj
    //    (K=512, independent, pre-scaled by EC) in one 1536-block dispatch.
    GemmJob jck = { ctx_bf, wsrk_p, bsrk, convk, 0, 8192,  2048, 1, 1.0f };
    GemmJob jcv = { ctx_bf, wsrv_p, bsrv, convv, 0, 8192,  2048, 1, 1.0f };
    GemmJob jq  = { x_bf,  wq_bf,  bq,   q_bf,  0, 32768, 512,  0, EC };
    gemm_multi<<<1536, 256, 0, stream>>>(jck, jcv, jq, 256, 256);

    // 3) both LayerNorms in one dispatch (convk||convv contiguous)
    ln_kernel<<<4096, 256, 0, stream>>>(convk, gk, bek, gv, bev);

    // 4) k+v projections as dual-job (512 blocks)
    GemmJob jk  = { convk, wk_bf, bk, k_bf,  0, 8192, 512, 0, 1.0f };
    GemmJob jv  = { convv, wv_bf, bv, vt_bf, 2, 8192, 512, 0, 1.0f };
    gemm_multi<<<512, 256, 0, stream>>>(jk, jv, jv, 256, 256);

    // 5) attention: 128 q-rows/block, 2 n-blocks/wave (Q pre-scaled, exp2 direct)
    attn_kernel<<<dim3(32, 8, 8), 256, 0, stream>>>(q_bf, k_bf, vt_bf, at_bf);

    // 6) output projection -> fp32 d_out
    GemmJob jo  = { at_bf, wp_bf, bp, d_out, 1, 32768, 512, 0, 1.0f };
    gemm_multi<<<1024, 256, 0, stream>>>(jo, jo, jo, 1024, 0);
}